// Round 3
// baseline (215.049 us; speedup 1.0000x reference)
//
#include <hip/hip_runtime.h>

// Yolov6 assigner pre-computation, fused:
//   distances[g][j] = ||center(gt_flat[g]) - center(anchor[j])||        (2048 x 8400)
//   overlaps[b][m][j] = IoU(gt[b][m], pred[b][j])   eps=1e-9 (added)    (16 x 128 x 8400)
//   gious[g][j]      = GIoU(gt_flat[g], anchor[j])  eps=1e-6 (clamped)  (2048 x 8400)
//
// Write-bandwidth-bound: 206.4 MB out, measured write ceiling 6.6 TB/s
// (harness fill) -> ~31 us kernel roofline.
// R5 = R4 with the nontemporal-store type fixed: the builtin requires a
// clang-native vector type, not HIP_vector_type float4 -> use
// ext_vector_type(4) alias. Otherwise unchanged:
// (a) exact 1-D grid (4200 blocks, zero dead threads), (b) single-rcp GIoU
// (overlap/u - (e-u)/e == (overlap*e - (e-u)*u) * rcp(u*e); trans pipe is
// quarter-rate), (c) nontemporal stores so the 206 MB write stream doesn't
// evict the 2.3 MB anchor/pred read set from L2.

#define EPS_IOU 1e-9f
#define EPS_OVL 1e-6f
#define ROWS 4

typedef float vfloat4 __attribute__((ext_vector_type(4)));  // clang-native, nt-store OK

__device__ __forceinline__ float frcp(float x)  { return __builtin_amdgcn_rcpf(x); }
__device__ __forceinline__ float fsqrtf_(float x){ return __builtin_amdgcn_sqrtf(x); }

__device__ __forceinline__ void nt_store4(float* p, float a, float b, float c, float d) {
    vfloat4 v; v.x = a; v.y = b; v.z = c; v.w = d;
    __builtin_nontemporal_store(v, (vfloat4*)p);
}

__global__ __launch_bounds__(256) void yolov6_fused(
    const float4* __restrict__ gt,    // bs*M boxes
    const float4* __restrict__ pred,  // bs*N boxes
    const float4* __restrict__ anc,   // N boxes
    float* __restrict__ out_dist,
    float* __restrict__ out_ovl,
    float* __restrict__ out_giou,
    int N, int M, int qcols, int total)   // qcols = ceil(N/4) threads per row-block
{
    const int t = blockIdx.x * blockDim.x + threadIdx.x;
    if (t >= total) return;               // exact fit for the bench shape (no-op)

    const int rb = t / qcols;             // row-block index (one u32 div/thread)
    const int c  = t - rb * qcols;
    const int j  = c * 4;                 // first anchor column (in boxes)
    if (j >= N) return;                   // defensive (never taken when 4|N)
    const int g0 = rb * ROWS;
    const int b  = g0 / M;                // ROWS | M so all ROWS rows share b

    // Load this thread's 4 anchor and 4 pred boxes ONCE; precompute
    // column-only quantities.
    float4 ab[4], pb[4];
    float acx[4], acy[4], aarea[4], parea[4];
    const float4* ancp  = anc + j;
    const float4* predp = pred + (long long)b * N + j;
#pragma unroll
    for (int k = 0; k < 4; ++k) {
        ab[k] = ancp[k];
        pb[k] = predp[k];
        acx[k]   = (ab[k].x + ab[k].z) * 0.5f;
        acy[k]   = (ab[k].y + ab[k].w) * 0.5f;
        aarea[k] = (ab[k].z - ab[k].x) * (ab[k].w - ab[k].y);
        parea[k] = (pb[k].z - pb[k].x) * (pb[k].w - pb[k].y);
    }

#pragma unroll
    for (int r = 0; r < ROWS; ++r) {
        const int g = g0 + r;
        const float4 gb = gt[g];          // wave-uniform except at rb seams
        const float gcx   = (gb.x + gb.z) * 0.5f;
        const float gcy   = (gb.y + gb.w) * 0.5f;
        const float garea = (gb.z - gb.x) * (gb.w - gb.y);

        float dv[4], ov[4], gv[4];
#pragma unroll
        for (int k = 0; k < 4; ++k) {
            // distance
            float dx = gcx - acx[k], dy = gcy - acy[k];
            dv[k] = fsqrtf_(dx * dx + dy * dy);
            // GIoU vs anchor — single rcp:
            //   overlap/uni - (earea-uni)/earea
            // = (overlap*earea - (earea-uni)*uni) * rcp(uni*earea)
            {
                float ltx = fmaxf(gb.x, ab[k].x), lty = fmaxf(gb.y, ab[k].y);
                float rbx = fminf(gb.z, ab[k].z), rby = fminf(gb.w, ab[k].w);
                float w = fmaxf(rbx - ltx, 0.0f), h = fmaxf(rby - lty, 0.0f);
                float overlap = w * h;
                float uni = fmaxf(garea + aarea[k] - overlap, EPS_OVL);
                float elx = fminf(gb.x, ab[k].x), ely = fminf(gb.y, ab[k].y);
                float erx = fmaxf(gb.z, ab[k].z), ery = fmaxf(gb.w, ab[k].w);
                float ew = fmaxf(erx - elx, 0.0f), eh = fmaxf(ery - ely, 0.0f);
                float earea = fmaxf(ew * eh, EPS_OVL);
                float num = overlap * earea - (earea - uni) * uni;
                gv[k] = num * frcp(uni * earea);
            }
            // IoU vs pred
            {
                float ltx = fmaxf(gb.x, pb[k].x), lty = fmaxf(gb.y, pb[k].y);
                float rbx = fminf(gb.z, pb[k].z), rby = fminf(gb.w, pb[k].w);
                float w = fmaxf(rbx - ltx, 0.0f), h = fmaxf(rby - lty, 0.0f);
                float overlap = w * h;
                float uni = garea + parea[k] - overlap + EPS_IOU;
                ov[k] = overlap * frcp(uni);
            }
        }
        const long long row = (long long)g * N + j;
        nt_store4(out_dist + row, dv[0], dv[1], dv[2], dv[3]);
        nt_store4(out_ovl  + row, ov[0], ov[1], ov[2], ov[3]);
        nt_store4(out_giou + row, gv[0], gv[1], gv[2], gv[3]);
    }
}

extern "C" void kernel_launch(void* const* d_in, const int* in_sizes, int n_in,
                              void* d_out, int out_size, void* d_ws, size_t ws_size,
                              hipStream_t stream) {
    const float4* gt   = (const float4*)d_in[0];
    const float4* pred = (const float4*)d_in[1];
    const float4* anc  = (const float4*)d_in[2];

    const int N  = in_sizes[2] / 4;           // 8400 anchors
    const int bs = in_sizes[1] / in_sizes[2]; // 16
    const int GM = in_sizes[0] / 4;           // bs*M = 2048
    const int M  = GM / bs;                   // 128

    float* out = (float*)d_out;
    const long long plane = (long long)GM * N;
    float* out_dist = out;
    float* out_ovl  = out + plane;
    float* out_giou = out + 2 * plane;

    const int qcols = (N + 3) / 4;            // 2100 threads per row-block
    const int total = (GM / ROWS) * qcols;    // 512 * 2100 = 1,075,200 (= 4200*256)
    dim3 block(256);
    dim3 grid((total + 255) / 256);
    yolov6_fused<<<grid, block, 0, stream>>>(gt, pred, anc,
                                             out_dist, out_ovl, out_giou,
                                             N, M, qcols, total);
}

// Round 4
// 213.991 us; speedup vs baseline: 1.0049x; 1.0049x over previous
//
#include <hip/hip_runtime.h>

// Yolov6 assigner pre-computation, fused:
//   distances[g][j] = ||center(gt_flat[g]) - center(anchor[j])||        (2048 x 8400)
//   overlaps[b][m][j] = IoU(gt[b][m], pred[b][j])   eps=1e-9 (added)    (16 x 128 x 8400)
//   gious[g][j]      = GIoU(gt_flat[g], anchor[j])  eps=1e-6 (clamped)  (2048 x 8400)
//
// Mandatory 206.4 MB out; measured write ceiling 6.35 TB/s (harness fill)
// -> 33 us store roofline. Kernel estimated ~80 us (envelope minus fill),
// insensitive to ALU/grid changes (R5) -> testing the store-drain/MLP
// theory: R6 forces 32 waves/CU via __launch_bounds__(256,8) (<=64 VGPR)
// with a 2x2 tile (register fixed cost: ab/pb 16 + derived 8), float2
// stores, no nt (let L2/L3 absorb; output < 256 MB L3). Exact-fit 1-D
// grid, single-rcp GIoU, fast rcp/sqrt retained.

#define EPS_IOU 1e-9f
#define EPS_OVL 1e-6f
#define ROWS 2
#define COLS 2

__device__ __forceinline__ float frcp(float x)   { return __builtin_amdgcn_rcpf(x); }
__device__ __forceinline__ float fsqrtf_(float x){ return __builtin_amdgcn_sqrtf(x); }

__global__ __launch_bounds__(256, 8) void yolov6_fused(
    const float4* __restrict__ gt,    // bs*M boxes
    const float4* __restrict__ pred,  // bs*N boxes
    const float4* __restrict__ anc,   // N boxes
    float* __restrict__ out_dist,
    float* __restrict__ out_ovl,
    float* __restrict__ out_giou,
    int N, int M, int qcols, int total)   // qcols = ceil(N/COLS) threads per row-block
{
    const int t = blockIdx.x * blockDim.x + threadIdx.x;
    if (t >= total) return;               // exact fit for the bench shape (no-op)

    const int rb = t / qcols;             // row-block index (one u32 div/thread)
    const int c  = t - rb * qcols;
    const int j  = c * COLS;              // first anchor column (in boxes)
    if (j + 1 >= N) return;               // defensive (never taken when COLS|N)
    const int g0 = rb * ROWS;
    const int b  = g0 / M;                // ROWS | M so both rows share b

    // Column-only data: 2 anchor + 2 pred boxes, loaded once.
    float4 ab[COLS], pb[COLS];
    float acx[COLS], acy[COLS], aarea[COLS], parea[COLS];
    const float4* ancp  = anc + j;
    const float4* predp = pred + (long long)b * N + j;
#pragma unroll
    for (int k = 0; k < COLS; ++k) {
        ab[k] = ancp[k];
        pb[k] = predp[k];
        acx[k]   = (ab[k].x + ab[k].z) * 0.5f;
        acy[k]   = (ab[k].y + ab[k].w) * 0.5f;
        aarea[k] = (ab[k].z - ab[k].x) * (ab[k].w - ab[k].y);
        parea[k] = (pb[k].z - pb[k].x) * (pb[k].w - pb[k].y);
    }

    const long long row0 = (long long)g0 * N + j;

#pragma unroll
    for (int r = 0; r < ROWS; ++r) {
        const float4 gb = gt[g0 + r];
        const float gcx   = (gb.x + gb.z) * 0.5f;
        const float gcy   = (gb.y + gb.w) * 0.5f;
        const float garea = (gb.z - gb.x) * (gb.w - gb.y);

        float dv[COLS], ov[COLS], gv[COLS];
#pragma unroll
        for (int k = 0; k < COLS; ++k) {
            // distance
            float dx = gcx - acx[k], dy = gcy - acy[k];
            dv[k] = fsqrtf_(dx * dx + dy * dy);
            // GIoU vs anchor — single rcp:
            //   overlap/uni - (earea-uni)/earea
            // = (overlap*earea - (earea-uni)*uni) * rcp(uni*earea)
            {
                float ltx = fmaxf(gb.x, ab[k].x), lty = fmaxf(gb.y, ab[k].y);
                float rbx = fminf(gb.z, ab[k].z), rby = fminf(gb.w, ab[k].w);
                float w = fmaxf(rbx - ltx, 0.0f), h = fmaxf(rby - lty, 0.0f);
                float overlap = w * h;
                float uni = fmaxf(garea + aarea[k] - overlap, EPS_OVL);
                float elx = fminf(gb.x, ab[k].x), ely = fminf(gb.y, ab[k].y);
                float erx = fmaxf(gb.z, ab[k].z), ery = fmaxf(gb.w, ab[k].w);
                float ew = fmaxf(erx - elx, 0.0f), eh = fmaxf(ery - ely, 0.0f);
                float earea = fmaxf(ew * eh, EPS_OVL);
                float num = overlap * earea - (earea - uni) * uni;
                gv[k] = num * frcp(uni * earea);
            }
            // IoU vs pred
            {
                float ltx = fmaxf(gb.x, pb[k].x), lty = fmaxf(gb.y, pb[k].y);
                float rbx = fminf(gb.z, pb[k].z), rby = fminf(gb.w, pb[k].w);
                float w = fmaxf(rbx - ltx, 0.0f), h = fmaxf(rby - lty, 0.0f);
                float overlap = w * h;
                float uni = garea + parea[k] - overlap + EPS_IOU;
                ov[k] = overlap * frcp(uni);
            }
        }
        const long long row = row0 + (long long)r * N;
        *(float2*)(out_dist + row) = make_float2(dv[0], dv[1]);
        *(float2*)(out_ovl  + row) = make_float2(ov[0], ov[1]);
        *(float2*)(out_giou + row) = make_float2(gv[0], gv[1]);
    }
}

extern "C" void kernel_launch(void* const* d_in, const int* in_sizes, int n_in,
                              void* d_out, int out_size, void* d_ws, size_t ws_size,
                              hipStream_t stream) {
    const float4* gt   = (const float4*)d_in[0];
    const float4* pred = (const float4*)d_in[1];
    const float4* anc  = (const float4*)d_in[2];

    const int N  = in_sizes[2] / 4;           // 8400 anchors
    const int bs = in_sizes[1] / in_sizes[2]; // 16
    const int GM = in_sizes[0] / 4;           // bs*M = 2048
    const int M  = GM / bs;                   // 128

    float* out = (float*)d_out;
    const long long plane = (long long)GM * N;
    float* out_dist = out;
    float* out_ovl  = out + plane;
    float* out_giou = out + 2 * plane;

    const int qcols = (N + COLS - 1) / COLS;  // 4200 threads per row-block
    const int total = (GM / ROWS) * qcols;    // 1024 * 4200 = 4,300,800 (= 16800*256)
    dim3 block(256);
    dim3 grid((total + 255) / 256);
    yolov6_fused<<<grid, block, 0, stream>>>(gt, pred, anc,
                                             out_dist, out_ovl, out_giou,
                                             N, M, qcols, total);
}